// Round 3
// baseline (1221.916 us; speedup 1.0000x reference)
//
#include <hip/hip_runtime.h>
#include <hip/hip_fp16.h>
#include <math.h>

#define NROWS 8192

typedef _Float16 half8 __attribute__((ext_vector_type(8)));
typedef _Float16 half4 __attribute__((ext_vector_type(4)));
typedef float f32x4 __attribute__((ext_vector_type(4)));

__device__ __forceinline__ f32x4 mfma16(half8 a, half8 b, f32x4 c) {
  return __builtin_amdgcn_mfma_f32_16x16x32_f16(a, b, c, 0, 0, 0);
}

#define SFENCE __builtin_amdgcn_sched_barrier(0)

__device__ __forceinline__ void dma16(const _Float16* g, _Float16* l) {
  __builtin_amdgcn_global_load_lds(
      (const __attribute__((address_space(1))) void*)g,
      (__attribute__((address_space(3))) void*)l, 16, 0, 0);
}

// ---------------------------------------------------------------------------
// prep: x (f32)->xh (f16); 5 weights -> transposed f16 WT[wi][n][k], coalesced
// via LDS 64x64 transpose tiles. blocks 0..255: x. blocks 256..575: W tiles.
// ---------------------------------------------------------------------------
__global__ __launch_bounds__(256) void prep(
    const float* __restrict__ x,
    const float* __restrict__ Wq, const float* __restrict__ Wk,
    const float* __restrict__ Wv, const float* __restrict__ Wf,
    const float* __restrict__ Wp,
    _Float16* __restrict__ xh, _Float16* __restrict__ WT)
{
  __shared__ float Ws[64][68];
  const int bid = blockIdx.x, tid = threadIdx.x;
  if (bid < 256) {
    const int base = bid * 16384 + tid * 4;
#pragma unroll
    for (int r = 0; r < 16; ++r) {
      float4 v = *(const float4*)(x + base + r * 1024);
      half4 h;
      h[0] = (_Float16)v.x; h[1] = (_Float16)v.y;
      h[2] = (_Float16)v.z; h[3] = (_Float16)v.w;
      *(half4*)(xh + base + r * 1024) = h;
    }
  } else {
    const int wb = bid - 256;          // 0..319
    const int wi = wb >> 6;            // 0..4
    const int tix = wb & 63;
    const int k0 = (tix >> 3) * 64;
    const int n0 = (tix & 7) * 64;
    const float* W = (wi == 0) ? Wq : (wi == 1) ? Wk : (wi == 2) ? Wv
                   : (wi == 3) ? Wf : Wp;
    const int r = tid >> 2, cq = tid & 3;
#pragma unroll
    for (int j = 0; j < 4; ++j) {
      float4 v = *(const float4*)(W + (size_t)(k0 + r) * 512 + n0 + cq * 16 + j * 4);
      *(float4*)&Ws[r][cq * 16 + j * 4] = v;
    }
    __syncthreads();
    const int n = tid >> 2, kq = tid & 3;
    half8 h0, h1;
#pragma unroll
    for (int m = 0; m < 8; ++m) h0[m] = (_Float16)Ws[kq * 16 + m][n];
#pragma unroll
    for (int m = 0; m < 8; ++m) h1[m] = (_Float16)Ws[kq * 16 + 8 + m][n];
    _Float16* dst = WT + (size_t)wi * 262144 + (size_t)(n0 + n) * 512 + k0 + kq * 16;
    *(half8*)dst = h0;
    *(half8*)(dst + 8) = h1;
  }
}

// ---------------------------------------------------------------------------
// Fused QKV (unchanged structure from round 2 — passed): M-tile 32, 8 waves,
// A staged in LDS, B-frags from L2-resident WT. V written transposed.
// ---------------------------------------------------------------------------
__global__ __launch_bounds__(512, 2) void qkv(
    const _Float16* __restrict__ xh, const _Float16* __restrict__ WT,
    const float* __restrict__ bq, const float* __restrict__ bk,
    const float* __restrict__ bv,
    _Float16* __restrict__ Qh, _Float16* __restrict__ Kh,
    _Float16* __restrict__ Vt)
{
  __shared__ _Float16 As[32][520];
  const int M0 = blockIdx.x * 32;
  const int tid = threadIdx.x;
  const int lane = tid & 63;
  const int w = tid >> 6;
  const int lr = lane & 15;
  const int lkb = lane >> 4;

#pragma unroll
  for (int j = 0; j < 4; ++j) {
    int c = tid + 512 * j;
    int r = c >> 6, c16 = c & 63;
    half8 h = *(const half8*)(xh + (size_t)(M0 + r) * 512 + c16 * 8);
    *(half8*)&As[r][c16 * 8] = h;
  }
  __syncthreads();

  const _Float16* WqT = WT;
  const _Float16* WkT = WT + 262144;
  const _Float16* WvT = WT + 524288;

  f32x4 aq[2][4] = {}, ak[2][4] = {}, av[2][4] = {};

  for (int ks = 0; ks < 16; ++ks) {
    half8 a0 = *(const half8*)&As[lr][ks * 32 + lkb * 8];
    half8 a1 = *(const half8*)&As[16 + lr][ks * 32 + lkb * 8];
#pragma unroll
    for (int nt = 0; nt < 4; ++nt) {
      const size_t boff = (size_t)(w * 64 + nt * 16 + lr) * 512 + ks * 32 + lkb * 8;
      half8 bqf = *(const half8*)(WqT + boff);
      half8 bkf = *(const half8*)(WkT + boff);
      half8 bvf = *(const half8*)(WvT + boff);
      aq[0][nt] = mfma16(a0, bqf, aq[0][nt]);
      aq[1][nt] = mfma16(a1, bqf, aq[1][nt]);
      ak[0][nt] = mfma16(a0, bkf, ak[0][nt]);
      ak[1][nt] = mfma16(a1, bkf, ak[1][nt]);
      av[0][nt] = mfma16(a0, bvf, av[0][nt]);
      av[1][nt] = mfma16(a1, bvf, av[1][nt]);
    }
  }

#pragma unroll
  for (int mt = 0; mt < 2; ++mt) {
#pragma unroll
    for (int nt = 0; nt < 4; ++nt) {
      const int col = w * 64 + nt * 16 + lr;
      const float vbq = bq[col], vbk = bk[col], vbv = bv[col];
      const int row0 = M0 + mt * 16 + lkb * 4;
#pragma unroll
      for (int i = 0; i < 4; ++i) {
        Qh[(size_t)(row0 + i) * 512 + col] = (_Float16)(aq[mt][nt][i] + vbq);
        Kh[(size_t)(row0 + i) * 512 + col] = (_Float16)(ak[mt][nt][i] + vbk);
      }
      half4 pk;
#pragma unroll
      for (int i = 0; i < 4; ++i) pk[i] = (_Float16)(av[mt][nt][i] + vbv);
      *(half4*)(Vt + (size_t)col * NROWS + row0) = pk;
    }
  }
}

// ---------------------------------------------------------------------------
// Retention v3: Xp[Jc] = (D ∘ (Q K^T)) V over J-chunk 4096.
// Block: I-tile 64, J-tile 64, 512 thr (8 waves). K staged via global_load_lds
// (linear LDS rows, XOR swizzle baked into per-lane global src). Q in regs
// (32 rows/wave). V-frags from global (L2) into regs, n-split across waves.
// Ps double-buffered + chunk-XOR swizzle. 2 raw barriers / tile.
// ---------------------------------------------------------------------------
__global__ __launch_bounds__(512, 2) void retention(
    const _Float16* __restrict__ Qh, const _Float16* __restrict__ Kh,
    const _Float16* __restrict__ Vt, const float* __restrict__ D,
    float* __restrict__ Xp0, float* __restrict__ Xp1)
{
  __shared__ _Float16 Ks[2][64][512];   // 128 KB
  __shared__ _Float16 Ps[2][64][64];    //  16 KB

  const int bid = blockIdx.x;
  const int Jc = bid & 1;
  const int I0 = (bid >> 1) * 64;
  const int Jbase = Jc * 4096;
  float* __restrict__ Xp = Jc ? Xp1 : Xp0;

  const int tid = threadIdx.x;
  const int lane = tid & 63;
  const int w = tid >> 6;
  const int wr = w >> 2;      // 0..1 : Q-row group of 32
  const int wc = w & 3;       // 0..3 : j-slice of 16
  const int lr = lane & 15;
  const int lkb = lane >> 4;

  // Q preload: 32 frags = rows I0 + wr*32 + it*16 + lr, k = kc*32 + lkb*8
  half8 q[2][16];
#pragma unroll
  for (int it = 0; it < 2; ++it) {
    const _Float16* qp = Qh + (size_t)(I0 + wr * 32 + it * 16 + lr) * 512 + lkb * 8;
#pragma unroll
    for (int kc = 0; kc < 16; ++kc) q[it][kc] = *(const half8*)(qp + kc * 32);
  }

  // prologue: DMA tile 0, prefetch D(0)
#pragma unroll
  for (int rr = 0; rr < 8; ++rr) {
    const int row = w * 8 + rr;
    dma16(Kh + (size_t)(Jbase + row) * 512 + ((lane ^ (row & 7)) * 8), &Ks[0][row][0]);
  }
  SFENCE;
  float dv[8];
#pragma unroll
  for (int it = 0; it < 2; ++it)
#pragma unroll
    for (int i = 0; i < 4; ++i)
      dv[it * 4 + i] = D[(size_t)(I0 + wr * 32 + it * 16 + lkb * 4 + i) * NROWS +
                         Jbase + wc * 16 + lr];
  asm volatile("s_waitcnt vmcnt(0)" ::: "memory");
  SFENCE;
  __builtin_amdgcn_s_barrier();

  f32x4 acc[4][4] = {};
  const int jrow = wc * 16 + lr;

  for (int t = 0; t < 64; ++t) {
    const int cb = t & 1;
    const int tn = (t + 1 < 64) ? t + 1 : 63;
    const int J0 = Jbase + t * 64;
    const int J0n = Jbase + tn * 64;

    // V(t) fragments -> regs (wave's n-slice of 64)
    half8 vreg[4][2];
#pragma unroll
    for (int nt = 0; nt < 4; ++nt)
#pragma unroll
      for (int k2 = 0; k2 < 2; ++k2)
        vreg[nt][k2] = *(const half8*)(Vt + (size_t)(w * 64 + nt * 16 + lr) * NROWS +
                                       J0 + k2 * 32 + lkb * 8);
    SFENCE;

    // QK^T: 32 MFMAs from Ks[cb] + Q regs
    f32x4 s0 = {}, s1 = {};
    const _Float16* ksb = &Ks[cb][0][0];
    __builtin_amdgcn_s_setprio(1);
#pragma unroll
    for (int kc = 0; kc < 16; ++kc) {
      half8 kb = *(const half8*)(ksb + jrow * 512 + (((kc * 4 + lkb) ^ (jrow & 7)) * 8));
      s0 = mfma16(q[0][kc], kb, s0);
      s1 = mfma16(q[1][kc], kb, s1);
    }
    __builtin_amdgcn_s_setprio(0);
    SFENCE;

    // DMA next K-tile into Ks[cb^1]
#pragma unroll
    for (int rr = 0; rr < 8; ++rr) {
      const int row = w * 8 + rr;
      dma16(Kh + (size_t)(J0n + row) * 512 + ((lane ^ (row & 7)) * 8),
            &Ks[cb ^ 1][row][0]);
    }
    SFENCE;

    // P = D*S -> f16 -> Ps[cb] (chunk-XOR swizzled)
    _Float16* psb = &Ps[cb][0][0];
#pragma unroll
    for (int it = 0; it < 2; ++it)
#pragma unroll
      for (int i = 0; i < 4; ++i) {
        const int prow = wr * 32 + it * 16 + lkb * 4 + i;
        const float sv = (it == 0 ? s0[i] : s1[i]) * dv[it * 4 + i];
        psb[prow * 64 + (((wc * 2 + (lr >> 3)) ^ (prow & 7)) * 8) + (lr & 7)] =
            (_Float16)sv;
      }

    // D(t+1) prefetch (dv free now)
#pragma unroll
    for (int it = 0; it < 2; ++it)
#pragma unroll
      for (int i = 0; i < 4; ++i)
        dv[it * 4 + i] = D[(size_t)(I0 + wr * 32 + it * 16 + lkb * 4 + i) * NROWS +
                           J0n + wc * 16 + lr];
    SFENCE;

    asm volatile("s_waitcnt lgkmcnt(0)" ::: "memory");
    SFENCE;
    __builtin_amdgcn_s_barrier();            // #A : Ps visible to all waves

    // PV: 8 Ps A-frag reads (x4 reuse) + V regs -> 32 MFMAs
    __builtin_amdgcn_s_setprio(1);
#pragma unroll
    for (int k2 = 0; k2 < 2; ++k2)
#pragma unroll
      for (int it = 0; it < 4; ++it) {
        const int prow = it * 16 + lr;
        half8 pa = *(const half8*)(psb + prow * 64 +
                                   (((k2 * 4 + lkb) ^ (prow & 7)) * 8));
#pragma unroll
        for (int nt = 0; nt < 4; ++nt)
          acc[it][nt] = mfma16(pa, vreg[nt][k2], acc[it][nt]);
      }
    __builtin_amdgcn_s_setprio(0);
    SFENCE;

    // drain DMA (cross-wave; compiler can't know) then release buffers
    asm volatile("s_waitcnt vmcnt(0)" ::: "memory");
    SFENCE;
    __builtin_amdgcn_s_barrier();            // #B
  }

#pragma unroll
  for (int it = 0; it < 4; ++it)
#pragma unroll
    for (int nt = 0; nt < 4; ++nt)
#pragma unroll
      for (int i = 0; i < 4; ++i)
        Xp[(size_t)(I0 + it * 16 + lkb * 4 + i) * 512 + w * 64 + nt * 16 + lr] =
            acc[it][nt][i];
}

// ---------------------------------------------------------------------------
// Fused MLP: h = gelu((Xp0+Xp1)@Wf + bf); out = GroupNorm(h@Wp + bp).
// h lives in LDS between the two GEMMs. GN fused in epilogue.
// ---------------------------------------------------------------------------
__global__ __launch_bounds__(512, 2) void mlp(
    const float* __restrict__ Xp0, const float* __restrict__ Xp1,
    const _Float16* __restrict__ WfT, const float* __restrict__ bf,
    const _Float16* __restrict__ WpT, const float* __restrict__ bp,
    const float* __restrict__ gamma, const float* __restrict__ beta,
    float* __restrict__ out)
{
  __shared__ _Float16 As[32][520];
  const int M0 = blockIdx.x * 32;
  const int tid = threadIdx.x;
  const int lane = tid & 63;
  const int w = tid >> 6;
  const int lr = lane & 15;
  const int lkb = lane >> 4;

#pragma unroll
  for (int j = 0; j < 4; ++j) {
    int c = tid + 512 * j;
    int r = c >> 6, c16 = c & 63;
    const size_t off = (size_t)(M0 + r) * 512 + c16 * 8;
    float4 a0 = *(const float4*)(Xp0 + off);
    float4 a1 = *(const float4*)(Xp0 + off + 4);
    float4 b0 = *(const float4*)(Xp1 + off);
    float4 b1 = *(const float4*)(Xp1 + off + 4);
    half8 h;
    h[0] = (_Float16)(a0.x + b0.x); h[1] = (_Float16)(a0.y + b0.y);
    h[2] = (_Float16)(a0.z + b0.z); h[3] = (_Float16)(a0.w + b0.w);
    h[4] = (_Float16)(a1.x + b1.x); h[5] = (_Float16)(a1.y + b1.y);
    h[6] = (_Float16)(a1.z + b1.z); h[7] = (_Float16)(a1.w + b1.w);
    *(half8*)&As[r][c16 * 8] = h;
  }
  __syncthreads();

  f32x4 acc[2][4] = {};
  for (int ks = 0; ks < 16; ++ks) {
    half8 a0 = *(const half8*)&As[lr][ks * 32 + lkb * 8];
    half8 a1 = *(const half8*)&As[16 + lr][ks * 32 + lkb * 8];
#pragma unroll
    for (int nt = 0; nt < 4; ++nt) {
      half8 b = *(const half8*)(WfT + (size_t)(w * 64 + nt * 16 + lr) * 512 +
                                ks * 32 + lkb * 8);
      acc[0][nt] = mfma16(a0, b, acc[0][nt]);
      acc[1][nt] = mfma16(a1, b, acc[1][nt]);
    }
  }
  __syncthreads();   // everyone done reading As

  // gelu -> h tile back into As
#pragma unroll
  for (int mt = 0; mt < 2; ++mt)
#pragma unroll
    for (int nt = 0; nt < 4; ++nt) {
      const int col = w * 64 + nt * 16 + lr;
      const float bias = bf[col];
#pragma unroll
      for (int i = 0; i < 4; ++i) {
        float v = acc[mt][nt][i] + bias;
        v = 0.5f * v * (1.0f + erff(v * 0.70710678118f));
        As[mt * 16 + lkb * 4 + i][col] = (_Float16)v;
      }
    }
  __syncthreads();

  f32x4 acc2[2][4] = {};
  for (int ks = 0; ks < 16; ++ks) {
    half8 a0 = *(const half8*)&As[lr][ks * 32 + lkb * 8];
    half8 a1 = *(const half8*)&As[16 + lr][ks * 32 + lkb * 8];
#pragma unroll
    for (int nt = 0; nt < 4; ++nt) {
      half8 b = *(const half8*)(WpT + (size_t)(w * 64 + nt * 16 + lr) * 512 +
                                ks * 32 + lkb * 8);
      acc2[0][nt] = mfma16(a0, b, acc2[0][nt]);
      acc2[1][nt] = mfma16(a1, b, acc2[1][nt]);
    }
  }

#pragma unroll
  for (int mt = 0; mt < 2; ++mt) {
    float vv[4][4];
#pragma unroll
    for (int nt = 0; nt < 4; ++nt) {
      const float bias = bp[w * 64 + nt * 16 + lr];
#pragma unroll
      for (int i = 0; i < 4; ++i) vv[nt][i] = acc2[mt][nt][i] + bias;
    }
#pragma unroll
    for (int i = 0; i < 4; ++i) {
      float s0 = vv[0][i] + vv[1][i];
      float q0 = vv[0][i] * vv[0][i] + vv[1][i] * vv[1][i];
      float s1 = vv[2][i] + vv[3][i];
      float q1 = vv[2][i] * vv[2][i] + vv[3][i] * vv[3][i];
#pragma unroll
      for (int m = 1; m <= 8; m <<= 1) {
        s0 += __shfl_xor(s0, m); q0 += __shfl_xor(q0, m);
        s1 += __shfl_xor(s1, m); q1 += __shfl_xor(q1, m);
      }
      const float mu0 = s0 * (1.0f / 32.0f);
      const float rs0 = rsqrtf(q0 * (1.0f / 32.0f) - mu0 * mu0 + 1e-5f);
      const float mu1 = s1 * (1.0f / 32.0f);
      const float rs1 = rsqrtf(q1 * (1.0f / 32.0f) - mu1 * mu1 + 1e-5f);
      const int row = M0 + mt * 16 + lkb * 4 + i;
#pragma unroll
      for (int nt = 0; nt < 4; ++nt) {
        const int col = w * 64 + nt * 16 + lr;
        const float mu = (nt < 2) ? mu0 : mu1;
        const float rs = (nt < 2) ? rs0 : rs1;
        out[(size_t)row * 512 + col] =
            (vv[nt][i] - mu) * rs * gamma[col] + beta[col];
      }
    }
  }
}

// ---------------------------------------------------------------------------
extern "C" void kernel_launch(void* const* d_in, const int* in_sizes, int n_in,
                              void* d_out, int out_size, void* d_ws, size_t ws_size,
                              hipStream_t stream)
{
  const float* x  = (const float*)d_in[0];
  const float* D  = (const float*)d_in[1];
  const float* Wq = (const float*)d_in[2];
  const float* bq = (const float*)d_in[3];
  const float* Wk = (const float*)d_in[4];
  const float* bk = (const float*)d_in[5];
  const float* Wv = (const float*)d_in[6];
  const float* bv = (const float*)d_in[7];
  const float* Wf = (const float*)d_in[8];
  const float* bf = (const float*)d_in[9];
  const float* Wp = (const float*)d_in[10];
  const float* bp = (const float*)d_in[11];
  const float* gamma = (const float*)d_in[12];
  const float* beta  = (const float*)d_in[13];

  char* ws = (char*)d_ws;
  const size_t MB = 1024 * 1024;
  _Float16* xh  = (_Float16*)(ws);               //  8 MB
  _Float16* WT  = (_Float16*)(ws + 8 * MB);      //  2.62 MB
  _Float16* Qh  = (_Float16*)(ws + 11 * MB);     //  8 MB
  _Float16* Kh  = (_Float16*)(ws + 19 * MB);     //  8 MB
  _Float16* Vt  = (_Float16*)(ws + 27 * MB);     //  8 MB (V transposed [n][m])
  float*    Xp0 = (float*)   (ws + 35 * MB);     // 16 MB
  float*    Xp1 = (float*)   (ws + 51 * MB);     // 16 MB

  hipLaunchKernelGGL(prep, dim3(576), dim3(256), 0, stream,
                     x, Wq, Wk, Wv, Wf, Wp, xh, WT);
  hipLaunchKernelGGL(qkv, dim3(256), dim3(512), 0, stream,
                     xh, WT, bq, bk, bv, Qh, Kh, Vt);
  hipLaunchKernelGGL(retention, dim3(256), dim3(512), 0, stream,
                     Qh, Kh, Vt, D, Xp0, Xp1);
  hipLaunchKernelGGL(mlp, dim3(256), dim3(512), 0, stream,
                     Xp0, Xp1, WT + 3 * 262144, bf, WT + 4 * 262144, bp,
                     gamma, beta, (float*)d_out);
}

// Round 4
// 801.499 us; speedup vs baseline: 1.5245x; 1.5245x over previous
//
#include <hip/hip_runtime.h>
#include <hip/hip_fp16.h>
#include <math.h>

#define NROWS 8192

typedef _Float16 half8 __attribute__((ext_vector_type(8)));
typedef _Float16 half4 __attribute__((ext_vector_type(4)));
typedef float f32x4 __attribute__((ext_vector_type(4)));

__device__ __forceinline__ f32x4 mfma16(half8 a, half8 b, f32x4 c) {
  return __builtin_amdgcn_mfma_f32_16x16x32_f16(a, b, c, 0, 0, 0);
}

// ---------------------------------------------------------------------------
// prep: x (f32)->xh (f16); 5 weights -> transposed f16 WT[wi][n][k] via LDS
// 64x64 transpose tiles. blocks 0..255: x. blocks 256..575: W tiles.
// ---------------------------------------------------------------------------
__global__ __launch_bounds__(256) void prep(
    const float* __restrict__ x,
    const float* __restrict__ Wq, const float* __restrict__ Wk,
    const float* __restrict__ Wv, const float* __restrict__ Wf,
    const float* __restrict__ Wp,
    _Float16* __restrict__ xh, _Float16* __restrict__ WT)
{
  __shared__ float Ws[64][68];
  const int bid = blockIdx.x, tid = threadIdx.x;
  if (bid < 256) {
    const int base = bid * 16384 + tid * 4;
#pragma unroll
    for (int r = 0; r < 16; ++r) {
      float4 v = *(const float4*)(x + base + r * 1024);
      half4 h;
      h[0] = (_Float16)v.x; h[1] = (_Float16)v.y;
      h[2] = (_Float16)v.z; h[3] = (_Float16)v.w;
      *(half4*)(xh + base + r * 1024) = h;
    }
  } else {
    const int wb = bid - 256;          // 0..319
    const int wi = wb >> 6;            // 0..4
    const int tix = wb & 63;
    const int k0 = (tix >> 3) * 64;
    const int n0 = (tix & 7) * 64;
    const float* W = (wi == 0) ? Wq : (wi == 1) ? Wk : (wi == 2) ? Wv
                   : (wi == 3) ? Wf : Wp;
    const int r = tid >> 2, cq = tid & 3;
#pragma unroll
    for (int j = 0; j < 4; ++j) {
      float4 v = *(const float4*)(W + (size_t)(k0 + r) * 512 + n0 + cq * 16 + j * 4);
      *(float4*)&Ws[r][cq * 16 + j * 4] = v;
    }
    __syncthreads();
    const int n = tid >> 2, kq = tid & 3;
    half8 h0, h1;
#pragma unroll
    for (int m = 0; m < 8; ++m) h0[m] = (_Float16)Ws[kq * 16 + m][n];
#pragma unroll
    for (int m = 0; m < 8; ++m) h1[m] = (_Float16)Ws[kq * 16 + 8 + m][n];
    _Float16* dst = WT + (size_t)wi * 262144 + (size_t)(n0 + n) * 512 + k0 + kq * 16;
    *(half8*)dst = h0;
    *(half8*)(dst + 8) = h1;
  }
}

// ---------------------------------------------------------------------------
// Fused QKV: M-tile 16, grid 512, 8 waves, n-slice 64/wave.
// ---------------------------------------------------------------------------
__global__ __launch_bounds__(512, 4) void qkv(
    const _Float16* __restrict__ xh, const _Float16* __restrict__ WT,
    const float* __restrict__ bq, const float* __restrict__ bk,
    const float* __restrict__ bv,
    _Float16* __restrict__ Qh, _Float16* __restrict__ Kh,
    _Float16* __restrict__ Vt)
{
  __shared__ _Float16 As[16][520];
  const int M0 = blockIdx.x * 16;
  const int tid = threadIdx.x;
  const int lane = tid & 63;
  const int w = tid >> 6;
  const int lr = lane & 15;
  const int lkb = lane >> 4;

#pragma unroll
  for (int j = 0; j < 2; ++j) {
    int idx = tid + 512 * j;
    int r = idx >> 6, c16 = idx & 63;
    half8 h = *(const half8*)(xh + (size_t)(M0 + r) * 512 + c16 * 8);
    *(half8*)&As[r][c16 * 8] = h;
  }
  __syncthreads();

  const _Float16* WqT = WT;
  const _Float16* WkT = WT + 262144;
  const _Float16* WvT = WT + 524288;

  f32x4 aq[4] = {}, ak[4] = {}, av[4] = {};

  for (int kc = 0; kc < 16; ++kc) {
    half8 a0 = *(const half8*)&As[lr][kc * 32 + lkb * 8];
#pragma unroll
    for (int nt = 0; nt < 4; ++nt) {
      const size_t boff = (size_t)(w * 64 + nt * 16 + lr) * 512 + kc * 32 + lkb * 8;
      aq[nt] = mfma16(a0, *(const half8*)(WqT + boff), aq[nt]);
      ak[nt] = mfma16(a0, *(const half8*)(WkT + boff), ak[nt]);
      av[nt] = mfma16(a0, *(const half8*)(WvT + boff), av[nt]);
    }
  }

#pragma unroll
  for (int nt = 0; nt < 4; ++nt) {
    const int col = w * 64 + nt * 16 + lr;
    const float vbq = bq[col], vbk = bk[col], vbv = bv[col];
    const int row0 = M0 + lkb * 4;
#pragma unroll
    for (int i = 0; i < 4; ++i) {
      Qh[(size_t)(row0 + i) * 512 + col] = (_Float16)(aq[nt][i] + vbq);
      Kh[(size_t)(row0 + i) * 512 + col] = (_Float16)(ak[nt][i] + vbk);
    }
    half4 pk;
#pragma unroll
    for (int i = 0; i < 4; ++i) pk[i] = (_Float16)(av[nt][i] + vbv);
    *(half4*)(Vt + (size_t)col * NROWS + row0) = pk;   // transposed, 8B store
  }
}

// ---------------------------------------------------------------------------
// Retention v4: Xp[Jc] = (D ∘ (Q K^T)) V per J-chunk. I-tile 64, J-tile 32,
// 8 waves. S^T orientation: mfma(K,Q) -> lane holds 4 consecutive j =>
// float4 D-load + packed 8B Ps write. K single-buffered LDS (reg-staged);
// Q in regs; V b-frags direct from L2-resident Vt; Ps single-buffered.
// 2 __syncthreads per tile; no manual waitcnt, no DMA.
// ---------------------------------------------------------------------------
__global__ __launch_bounds__(512, 2) void retention(
    const _Float16* __restrict__ Qh, const _Float16* __restrict__ Kh,
    const _Float16* __restrict__ Vt, const float* __restrict__ Dm,
    float* __restrict__ XpBase, int lg)
{
  __shared__ _Float16 Ks[32][520];   // 33.3 KB, K-tile rows x k (padded)
  __shared__ _Float16 Ps[64][40];    //  5.1 KB, P rows(i) x j (padded)

  const int bid = blockIdx.x;
  const int Jc = bid & ((1 << lg) - 1);
  const int I0 = (bid >> lg) * 64;
  const int Jchunk = NROWS >> lg;
  const int Jbase = Jc * Jchunk;
  const int NT = Jchunk >> 5;
  float* __restrict__ Xp = XpBase + (size_t)Jc * NROWS * 512;

  const int tid = threadIdx.x;
  const int lane = tid & 63;
  const int w = tid >> 6;
  const int g = w >> 1;       // 0..3 : i row-group of 16
  const int js = w & 1;       // 0..1 : j-slice of 16
  const int lr = lane & 15;
  const int lkb = lane >> 4;

  // Q B-frags (col=i=lr, k): rows I0+g*16+lr, 16 frags = full K=512
  half8 q[16];
  {
    const _Float16* qp = Qh + (size_t)(I0 + g * 16 + lr) * 512 + lkb * 8;
#pragma unroll
    for (int kc = 0; kc < 16; ++kc) q[kc] = *(const half8*)(qp + kc * 32);
  }

  int krow[4], kc16[4];
#pragma unroll
  for (int j = 0; j < 4; ++j) {
    int idx = tid + 512 * j;
    krow[j] = idx >> 6; kc16[j] = idx & 63;
  }

  // prologue: stage K tile 0
#pragma unroll
  for (int j = 0; j < 4; ++j) {
    half8 kd = *(const half8*)(Kh + (size_t)(Jbase + krow[j]) * 512 + kc16[j] * 8);
    *(half8*)&Ks[krow[j]][kc16[j] * 8] = kd;
  }
  __syncthreads();

  f32x4 acc[4][4] = {};

  for (int t = 0; t < NT; ++t) {
    const int Jb = Jbase + t * 32;
    const bool more = (t + 1 < NT);
    const int Jn = more ? Jb + 32 : Jb;

    // issue-early globals: K(t+1) -> regs, V(t) b-frags, D(t) float4
    half8 kreg[4];
#pragma unroll
    for (int j = 0; j < 4; ++j)
      kreg[j] = *(const half8*)(Kh + (size_t)(Jn + krow[j]) * 512 + kc16[j] * 8);

    half8 vreg[4];
#pragma unroll
    for (int nt = 0; nt < 4; ++nt)
      vreg[nt] = *(const half8*)(Vt + (size_t)(w * 64 + nt * 16 + lr) * NROWS +
                                 Jb + lkb * 8);

    float4 dq = *(const float4*)(Dm + (size_t)(I0 + g * 16 + lr) * NROWS +
                                 Jb + js * 16 + lkb * 4);

    // S^T = K(tile-rows j) x Q(cols i): lane -> i=lr, j=4*lkb+ii
    f32x4 s0 = {}, s1 = {};
    const _Float16* kp = &Ks[js * 16 + lr][lkb * 8];
    __builtin_amdgcn_s_setprio(1);
#pragma unroll
    for (int kc = 0; kc < 16; kc += 2) {
      s0 = mfma16(*(const half8*)(kp + kc * 32), q[kc], s0);
      s1 = mfma16(*(const half8*)(kp + (kc + 1) * 32), q[kc + 1], s1);
    }
    __builtin_amdgcn_s_setprio(0);

    // P = D*S -> f16, one 8B packed write (4 consecutive j)
    half4 ph;
    ph[0] = (_Float16)((s0[0] + s1[0]) * dq.x);
    ph[1] = (_Float16)((s0[1] + s1[1]) * dq.y);
    ph[2] = (_Float16)((s0[2] + s1[2]) * dq.z);
    ph[3] = (_Float16)((s0[3] + s1[3]) * dq.w);
    *(half4*)&Ps[g * 16 + lr][js * 16 + lkb * 4] = ph;

    __syncthreads();   // A: Ps complete; Ks reads done

    // PV: 4 A-frag reads (x4 reuse) + V regs -> 16 independent MFMAs
    __builtin_amdgcn_s_setprio(1);
#pragma unroll
    for (int rt = 0; rt < 4; ++rt) {
      half8 pa = *(const half8*)&Ps[rt * 16 + lr][lkb * 8];
#pragma unroll
      for (int nt = 0; nt < 4; ++nt)
        acc[rt][nt] = mfma16(pa, vreg[nt], acc[rt][nt]);
    }
    __builtin_amdgcn_s_setprio(0);

    // stage K(t+1) into (single-buffered) Ks
    if (more) {
#pragma unroll
      for (int j = 0; j < 4; ++j)
        *(half8*)&Ks[krow[j]][kc16[j] * 8] = kreg[j];
    }
    __syncthreads();   // B: Ks(t+1) ready; Ps free for next tile
  }

#pragma unroll
  for (int rt = 0; rt < 4; ++rt)
#pragma unroll
    for (int nt = 0; nt < 4; ++nt)
#pragma unroll
      for (int i = 0; i < 4; ++i)
        Xp[(size_t)(I0 + rt * 16 + lkb * 4 + i) * 512 + w * 64 + nt * 16 + lr] =
            acc[rt][nt][i];
}

// ---------------------------------------------------------------------------
// Fused MLP: h = gelu((sum_c Xp_c)@Wf+bf); out = GroupNorm(h@Wp+bp).
// M-tile 16, grid 512. h round-trips through As. GN fused in epilogue.
// ---------------------------------------------------------------------------
__global__ __launch_bounds__(512, 4) void mlp(
    const float* __restrict__ Xp, int nc,
    const _Float16* __restrict__ WfT, const float* __restrict__ bf,
    const _Float16* __restrict__ WpT, const float* __restrict__ bp,
    const float* __restrict__ gamma, const float* __restrict__ beta,
    float* __restrict__ out)
{
  __shared__ _Float16 As[16][520];
  const int M0 = blockIdx.x * 16;
  const int tid = threadIdx.x;
  const int lane = tid & 63;
  const int w = tid >> 6;
  const int lr = lane & 15;
  const int lkb = lane >> 4;
  const size_t CH = (size_t)NROWS * 512;

#pragma unroll
  for (int j = 0; j < 2; ++j) {
    int idx = tid + 512 * j;
    int r = idx >> 6, c16 = idx & 63;
    size_t off = (size_t)(M0 + r) * 512 + c16 * 8;
    float a8[8] = {};
    for (int c = 0; c < nc; ++c) {
      float4 f0 = *(const float4*)(Xp + c * CH + off);
      float4 f1 = *(const float4*)(Xp + c * CH + off + 4);
      a8[0] += f0.x; a8[1] += f0.y; a8[2] += f0.z; a8[3] += f0.w;
      a8[4] += f1.x; a8[5] += f1.y; a8[6] += f1.z; a8[7] += f1.w;
    }
    half8 h;
#pragma unroll
    for (int m = 0; m < 8; ++m) h[m] = (_Float16)a8[m];
    *(half8*)&As[r][c16 * 8] = h;
  }
  __syncthreads();

  f32x4 a1[4] = {};
  for (int kc = 0; kc < 16; ++kc) {
    half8 a0 = *(const half8*)&As[lr][kc * 32 + lkb * 8];
#pragma unroll
    for (int nt = 0; nt < 4; ++nt) {
      half8 b = *(const half8*)(WfT + (size_t)(w * 64 + nt * 16 + lr) * 512 +
                                kc * 32 + lkb * 8);
      a1[nt] = mfma16(a0, b, a1[nt]);
    }
  }
  __syncthreads();   // all waves done reading As

#pragma unroll
  for (int nt = 0; nt < 4; ++nt) {
    const int col = w * 64 + nt * 16 + lr;
    const float bias = bf[col];
#pragma unroll
    for (int i = 0; i < 4; ++i) {
      float v = a1[nt][i] + bias;
      v = 0.5f * v * (1.0f + erff(v * 0.70710678118f));
      As[lkb * 4 + i][col] = (_Float16)v;
    }
  }
  __syncthreads();

  f32x4 a2[4] = {};
  for (int kc = 0; kc < 16; ++kc) {
    half8 a0 = *(const half8*)&As[lr][kc * 32 + lkb * 8];
#pragma unroll
    for (int nt = 0; nt < 4; ++nt) {
      half8 b = *(const half8*)(WpT + (size_t)(w * 64 + nt * 16 + lr) * 512 +
                                kc * 32 + lkb * 8);
      a2[nt] = mfma16(a0, b, a2[nt]);
    }
  }

  float vv[4][4];
#pragma unroll
  for (int nt = 0; nt < 4; ++nt) {
    const float bias = bp[w * 64 + nt * 16 + lr];
#pragma unroll
    for (int i = 0; i < 4; ++i) vv[nt][i] = a2[nt][i] + bias;
  }
#pragma unroll
  for (int i = 0; i < 4; ++i) {
    float s0 = vv[0][i] + vv[1][i];
    float q0 = vv[0][i] * vv[0][i] + vv[1][i] * vv[1][i];
    float s1 = vv[2][i] + vv[3][i];
    float q1 = vv[2][i] * vv[2][i] + vv[3][i] * vv[3][i];
#pragma unroll
    for (int m = 1; m <= 8; m <<= 1) {
      s0 += __shfl_xor(s0, m); q0 += __shfl_xor(q0, m);
      s1 += __shfl_xor(s1, m); q1 += __shfl_xor(q1, m);
    }
    const float mu0 = s0 * (1.0f / 32.0f);
    const float rs0 = rsqrtf(q0 * (1.0f / 32.0f) - mu0 * mu0 + 1e-5f);
    const float mu1 = s1 * (1.0f / 32.0f);
    const float rs1 = rsqrtf(q1 * (1.0f / 32.0f) - mu1 * mu1 + 1e-5f);
    const int row = M0 + lkb * 4 + i;
#pragma unroll
    for (int nt = 0; nt < 4; ++nt) {
      const int col = w * 64 + nt * 16 + lr;
      const float mu = (nt < 2) ? mu0 : mu1;
      const float rs = (nt < 2) ? rs0 : rs1;
      out[(size_t)row * 512 + col] =
          (vv[nt][i] - mu) * rs * gamma[col] + beta[col];
    }
  }
}

// ---------------------------------------------------------------------------
extern "C" void kernel_launch(void* const* d_in, const int* in_sizes, int n_in,
                              void* d_out, int out_size, void* d_ws, size_t ws_size,
                              hipStream_t stream)
{
  const float* x  = (const float*)d_in[0];
  const float* Dm = (const float*)d_in[1];
  const float* Wq = (const float*)d_in[2];
  const float* bq = (const float*)d_in[3];
  const float* Wk = (const float*)d_in[4];
  const float* bk = (const float*)d_in[5];
  const float* Wv = (const float*)d_in[6];
  const float* bv = (const float*)d_in[7];
  const float* Wf = (const float*)d_in[8];
  const float* bf = (const float*)d_in[9];
  const float* Wp = (const float*)d_in[10];
  const float* bp = (const float*)d_in[11];
  const float* gamma = (const float*)d_in[12];
  const float* beta  = (const float*)d_in[13];

  char* ws = (char*)d_ws;
  const size_t MB = 1024 * 1024;
  _Float16* xh  = (_Float16*)(ws);               //  8 MB
  _Float16* WT  = (_Float16*)(ws + 8 * MB);      //  2.62 MB
  _Float16* Qh  = (_Float16*)(ws + 11 * MB);     //  8 MB
  _Float16* Kh  = (_Float16*)(ws + 19 * MB);     //  8 MB
  _Float16* Vt  = (_Float16*)(ws + 27 * MB);     //  8 MB (V transposed [n][m])
  float*    Xp  = (float*)   (ws + 35 * MB);     // nc x 16 MB partials

  // nc=4 (better L2 chunk locality) if workspace allows, else proven nc=2
  const int lg = (ws_size >= 99 * MB) ? 2 : 1;
  const int nc = 1 << lg;

  hipLaunchKernelGGL(prep, dim3(576), dim3(256), 0, stream,
                     x, Wq, Wk, Wv, Wf, Wp, xh, WT);
  hipLaunchKernelGGL(qkv, dim3(512), dim3(512), 0, stream,
                     xh, WT, bq, bk, bv, Qh, Kh, Vt);
  hipLaunchKernelGGL(retention, dim3(128 << lg), dim3(512), 0, stream,
                     Qh, Kh, Vt, Dm, Xp, lg);
  hipLaunchKernelGGL(mlp, dim3(512), dim3(512), 0, stream,
                     Xp, nc, WT + 3 * 262144, bf, WT + 4 * 262144, bp,
                     gamma, beta, (float*)d_out);
}